// Round 6
// baseline (121.144 us; speedup 1.0000x reference)
//
#include <hip/hip_runtime.h>
#include <hip/hip_bf16.h>

#define BLOCK   256
#define QPT     8      // queries per thread
#define DCHUNKS 64     // db split into this many chunks (grid.y)
#define CHUNK   256    // db points per chunk = 16384/64

typedef __attribute__((ext_vector_type(16))) float f32x16;

// Pack both clouds into float4 (x,y,z,|p|^2), init min arrays to +inf bits,
// zero the output accumulator (stream-ordered before reduce's atomicAdds).
__global__ __launch_bounds__(BLOCK) void chamfer_prep(
    const float* __restrict__ Xc, const float* __restrict__ Xt,
    float4* __restrict__ Pc, float4* __restrict__ Pt,
    unsigned* __restrict__ minC, unsigned* __restrict__ minT,
    float* __restrict__ out, int n, int m)
{
    int i = blockIdx.x * BLOCK + threadIdx.x;
    if (i == 0) out[0] = 0.0f;
    if (i < n) {
        float x = Xc[i * 3 + 0], y = Xc[i * 3 + 1], z = Xc[i * 3 + 2];
        Pc[i] = make_float4(x, y, z, x * x + y * y + z * z);
        minC[i] = 0xFFFFFFFFu;
    }
    if (i < m) {
        float x = Xt[i * 3 + 0], y = Xt[i * 3 + 1], z = Xt[i * 3 + 2];
        Pt[i] = make_float4(x, y, z, x * x + y * y + z * z);
        minT[i] = 0xFFFFFFFFu;
    }
}

// Both directions in one launch (blockIdx.z picks roles). db points are
// wave-uniform: stream them through the SCALAR pipe. Each iteration does ONE
// s_load_dwordx16 (4 points, 64B) with its s_waitcnt lgkmcnt(0) fused in the
// SAME asm block (SMEM completes out-of-order, so full-wait single-buffering
// is the only sound pattern; latency is hidden by 4 waves/SIMD of TLP).
// No LDS, no barrier. Tracks min over db of (|p|^2 - 2 q.p); q^2 in epilogue.
// Inner cost: 3 v_fma + 0.5 v_min3 per (query,db) pair.
__global__ __launch_bounds__(BLOCK) void chamfer_pass(
    const float4* __restrict__ Pc, const float4* __restrict__ Pt,
    unsigned* __restrict__ minC, unsigned* __restrict__ minT)
{
    const float4* q; const float4* db; unsigned* minOut;
    if (blockIdx.z == 0) { q = Pc; db = Pt; minOut = minC; }
    else                 { q = Pt; db = Pc; minOut = minT; }

    const int qbase = blockIdx.x * (BLOCK * QPT);
    const int dbase = blockIdx.y * CHUNK;

    // This thread's QPT query points: premultiply by -2, keep q2 for epilogue
    float qx2[QPT], qy2[QPT], qz2[QPT], q2[QPT], mn[QPT];
#pragma unroll
    for (int k = 0; k < QPT; ++k) {
        float4 v = q[qbase + k * BLOCK + threadIdx.x];
        qx2[k] = -2.0f * v.x;
        qy2[k] = -2.0f * v.y;
        qz2[k] = -2.0f * v.z;
        q2[k]  = v.w;
        mn[k]  = 3.4e38f;
    }

    const char* dptr = (const char*)(db + dbase);

    for (int j = 0; j < CHUNK; j += 4) {
        f32x16 c;
        // Load 4 points into SGPRs and wait for them, atomically paired so no
        // consumer can slip before the waitcnt (the R4 bug class).
        asm volatile("s_load_dwordx16 %0, %1, 0x0\n\t"
                     "s_waitcnt lgkmcnt(0)"
                     : "=s"(c) : "s"(dptr + (size_t)j * 16));

        float p0x = c[0],  p0y = c[1],  p0z = c[2],  p0w = c[3];
        float p1x = c[4],  p1y = c[5],  p1z = c[6],  p1w = c[7];
        float p2x = c[8],  p2y = c[9],  p2z = c[10], p2w = c[11];
        float p3x = c[12], p3y = c[13], p3z = c[14], p3w = c[15];

#pragma unroll
        for (int k = 0; k < QPT; ++k) {
            float a0 = fmaf(qx2[k], p0x, p0w);
            a0 = fmaf(qy2[k], p0y, a0);
            a0 = fmaf(qz2[k], p0z, a0);
            float a1 = fmaf(qx2[k], p1x, p1w);
            a1 = fmaf(qy2[k], p1y, a1);
            a1 = fmaf(qz2[k], p1z, a1);
            float a2 = fmaf(qx2[k], p2x, p2w);
            a2 = fmaf(qy2[k], p2y, a2);
            a2 = fmaf(qz2[k], p2z, a2);
            float a3 = fmaf(qx2[k], p3x, p3w);
            a3 = fmaf(qy2[k], p3y, a3);
            a3 = fmaf(qz2[k], p3z, a3);
            // min3(a0, a1, min3(a2, a3, mn)) -> 2 v_min3_f32
            mn[k] = fminf(fminf(a0, a1), fminf(fminf(a2, a3), mn[k]));
        }
    }

    // d2 = max(mn + q2, 0) >= 0, so uint compare == float compare
#pragma unroll
    for (int k = 0; k < QPT; ++k) {
        float d = fmaxf(mn[k] + q2[k], 0.0f);
        atomicMin(&minOut[qbase + k * BLOCK + threadIdx.x], __float_as_uint(d));
    }
}

// Multi-block reduce: block partial sums -> one atomicAdd per block.
#define RBLOCKS 128
__global__ __launch_bounds__(BLOCK) void chamfer_reduce(
    const unsigned* __restrict__ minC, const unsigned* __restrict__ minT,
    float* __restrict__ out, int n, int m)
{
    __shared__ float red[4];
    float s = 0.0f;
    const float invn = 1.0f / (float)n, invm = 1.0f / (float)m;
    for (int i = blockIdx.x * BLOCK + threadIdx.x; i < n; i += RBLOCKS * BLOCK)
        s += __uint_as_float(minC[i]) * invn;
    for (int i = blockIdx.x * BLOCK + threadIdx.x; i < m; i += RBLOCKS * BLOCK)
        s += __uint_as_float(minT[i]) * invm;

#pragma unroll
    for (int off = 32; off > 0; off >>= 1) s += __shfl_down(s, off, 64);
    int wave = threadIdx.x >> 6;
    int lane = threadIdx.x & 63;
    if (lane == 0) red[wave] = s;
    __syncthreads();
    if (threadIdx.x == 0) {
        float t = red[0] + red[1] + red[2] + red[3];
        atomicAdd(out, t);
    }
}

extern "C" void kernel_launch(void* const* d_in, const int* in_sizes, int n_in,
                              void* d_out, int out_size, void* d_ws, size_t ws_size,
                              hipStream_t stream) {
    const float* Xc = (const float*)d_in[0];
    const float* Xt = (const float*)d_in[1];
    const int n = in_sizes[0] / 3;   // 16384
    const int m = in_sizes[1] / 3;   // 16384

    // ws layout: minC[n] u32 | minT[m] u32 | Pc[n] float4 | Pt[m] float4
    unsigned* minC = (unsigned*)d_ws;
    unsigned* minT = minC + n;
    float4*   Pc   = (float4*)((char*)d_ws + (size_t)(n + m) * sizeof(unsigned));
    float4*   Pt   = Pc + n;
    float*    out  = (float*)d_out;

    int prepBlocks = ((n > m ? n : m) + BLOCK - 1) / BLOCK;
    chamfer_prep<<<prepBlocks, BLOCK, 0, stream>>>(
        Xc, Xt, Pc, Pt, minC, minT, out, n, m);

    dim3 grid(n / (BLOCK * QPT), DCHUNKS, 2);   // 8 x 64 x 2 = 1024 blocks
    chamfer_pass<<<grid, BLOCK, 0, stream>>>(Pc, Pt, minC, minT);

    chamfer_reduce<<<RBLOCKS, BLOCK, 0, stream>>>(minC, minT, out, n, m);
}

// Round 7
// 100.397 us; speedup vs baseline: 1.2066x; 1.2066x over previous
//
#include <hip/hip_runtime.h>
#include <hip/hip_bf16.h>

#define BLOCK   256
#define QPT     16     // queries per thread (key knob: LDS reuse per ds_read)
#define DCHUNKS 128    // db split into this many chunks (grid.y)
#define CHUNK   128    // db points per chunk = 16384/128

// Pack both clouds into float4 (x,y,z,|p|^2), init min arrays to +inf bits,
// zero the output accumulator (stream-ordered before reduce's atomicAdds).
__global__ __launch_bounds__(BLOCK) void chamfer_prep(
    const float* __restrict__ Xc, const float* __restrict__ Xt,
    float4* __restrict__ Pc, float4* __restrict__ Pt,
    unsigned* __restrict__ minC, unsigned* __restrict__ minT,
    float* __restrict__ out, int n, int m)
{
    int i = blockIdx.x * BLOCK + threadIdx.x;
    if (i == 0) out[0] = 0.0f;
    if (i < n) {
        float x = Xc[i * 3 + 0], y = Xc[i * 3 + 1], z = Xc[i * 3 + 2];
        Pc[i] = make_float4(x, y, z, x * x + y * y + z * z);
        minC[i] = 0xFFFFFFFFu;
    }
    if (i < m) {
        float x = Xt[i * 3 + 0], y = Xt[i * 3 + 1], z = Xt[i * 3 + 2];
        Pt[i] = make_float4(x, y, z, x * x + y * y + z * z);
        minT[i] = 0xFFFFFFFFu;
    }
}

// Both directions in one launch (blockIdx.z picks roles). db chunk staged in
// LDS; each ds_read_b128 broadcast feeds 16 query-chains (QPT=16), so the
// LDS pipe runs at ~43% of VALU and VALU is the sole bottleneck.
// Tracks min over db of (|p|^2 - 2 q.p); q^2 added in the epilogue.
// Inner cost: 3 v_fma + 0.5 v_min3 per (query,db) pair.
__global__ __launch_bounds__(BLOCK, 4) void chamfer_pass(
    const float4* __restrict__ Pc, const float4* __restrict__ Pt,
    unsigned* __restrict__ minC, unsigned* __restrict__ minT)
{
    __shared__ float4 tile[CHUNK];   // 2 KB

    const float4* q; const float4* db; unsigned* minOut;
    if (blockIdx.z == 0) { q = Pc; db = Pt; minOut = minC; }
    else                 { q = Pt; db = Pc; minOut = minT; }

    const int qbase = blockIdx.x * (BLOCK * QPT);
    const int dbase = blockIdx.y * CHUNK;

    // Stage db chunk (coalesced float4 copy; threads >= CHUNK idle here)
    if (threadIdx.x < CHUNK) tile[threadIdx.x] = db[dbase + threadIdx.x];

    // This thread's QPT query points: premultiply by -2, keep q2 for epilogue
    float qx2[QPT], qy2[QPT], qz2[QPT], q2[QPT], mn[QPT];
#pragma unroll
    for (int k = 0; k < QPT; ++k) {
        float4 v = q[qbase + k * BLOCK + threadIdx.x];
        qx2[k] = -2.0f * v.x;
        qy2[k] = -2.0f * v.y;
        qz2[k] = -2.0f * v.z;
        q2[k]  = v.w;
        mn[k]  = 3.4e38f;
    }
    __syncthreads();

    // 4 db points per iteration; 16 queries x (12 fma + 2 min3) each.
#pragma unroll 2
    for (int j = 0; j < CHUNK; j += 4) {
        float4 p0 = tile[j + 0];
        float4 p1 = tile[j + 1];
        float4 p2 = tile[j + 2];
        float4 p3 = tile[j + 3];
#pragma unroll
        for (int k = 0; k < QPT; ++k) {
            float a0 = fmaf(qx2[k], p0.x, p0.w);
            a0 = fmaf(qy2[k], p0.y, a0);
            a0 = fmaf(qz2[k], p0.z, a0);
            float a1 = fmaf(qx2[k], p1.x, p1.w);
            a1 = fmaf(qy2[k], p1.y, a1);
            a1 = fmaf(qz2[k], p1.z, a1);
            float a2 = fmaf(qx2[k], p2.x, p2.w);
            a2 = fmaf(qy2[k], p2.y, a2);
            a2 = fmaf(qz2[k], p2.z, a2);
            float a3 = fmaf(qx2[k], p3.x, p3.w);
            a3 = fmaf(qy2[k], p3.y, a3);
            a3 = fmaf(qz2[k], p3.z, a3);
            // min3(a0, a1, min3(a2, a3, mn)) -> 2 v_min3_f32
            mn[k] = fminf(fminf(a0, a1), fminf(fminf(a2, a3), mn[k]));
        }
    }

    // d2 = max(mn + q2, 0) >= 0, so uint compare == float compare
#pragma unroll
    for (int k = 0; k < QPT; ++k) {
        float d = fmaxf(mn[k] + q2[k], 0.0f);
        atomicMin(&minOut[qbase + k * BLOCK + threadIdx.x], __float_as_uint(d));
    }
}

// Multi-block reduce: block partial sums -> one atomicAdd per block.
#define RBLOCKS 128
__global__ __launch_bounds__(BLOCK) void chamfer_reduce(
    const unsigned* __restrict__ minC, const unsigned* __restrict__ minT,
    float* __restrict__ out, int n, int m)
{
    __shared__ float red[4];
    float s = 0.0f;
    const float invn = 1.0f / (float)n, invm = 1.0f / (float)m;
    for (int i = blockIdx.x * BLOCK + threadIdx.x; i < n; i += RBLOCKS * BLOCK)
        s += __uint_as_float(minC[i]) * invn;
    for (int i = blockIdx.x * BLOCK + threadIdx.x; i < m; i += RBLOCKS * BLOCK)
        s += __uint_as_float(minT[i]) * invm;

#pragma unroll
    for (int off = 32; off > 0; off >>= 1) s += __shfl_down(s, off, 64);
    int wave = threadIdx.x >> 6;
    int lane = threadIdx.x & 63;
    if (lane == 0) red[wave] = s;
    __syncthreads();
    if (threadIdx.x == 0) {
        float t = red[0] + red[1] + red[2] + red[3];
        atomicAdd(out, t);
    }
}

extern "C" void kernel_launch(void* const* d_in, const int* in_sizes, int n_in,
                              void* d_out, int out_size, void* d_ws, size_t ws_size,
                              hipStream_t stream) {
    const float* Xc = (const float*)d_in[0];
    const float* Xt = (const float*)d_in[1];
    const int n = in_sizes[0] / 3;   // 16384
    const int m = in_sizes[1] / 3;   // 16384

    // ws layout: minC[n] u32 | minT[m] u32 | Pc[n] float4 | Pt[m] float4
    unsigned* minC = (unsigned*)d_ws;
    unsigned* minT = minC + n;
    float4*   Pc   = (float4*)((char*)d_ws + (size_t)(n + m) * sizeof(unsigned));
    float4*   Pt   = Pc + n;
    float*    out  = (float*)d_out;

    int prepBlocks = ((n > m ? n : m) + BLOCK - 1) / BLOCK;
    chamfer_prep<<<prepBlocks, BLOCK, 0, stream>>>(
        Xc, Xt, Pc, Pt, minC, minT, out, n, m);

    dim3 grid(n / (BLOCK * QPT), DCHUNKS, 2);   // 4 x 128 x 2 = 1024 blocks
    chamfer_pass<<<grid, BLOCK, 0, stream>>>(Pc, Pt, minC, minT);

    chamfer_reduce<<<RBLOCKS, BLOCK, 0, stream>>>(minC, minT, out, n, m);
}